// Round 2
// baseline (329.626 us; speedup 1.0000x reference)
//
#include <hip/hip_runtime.h>

typedef unsigned long long ull;
typedef float f4 __attribute__((ext_vector_type(4)));  // native vector: works with nontemporal builtins

__constant__ unsigned kSizes[16] = {
    6619u, 6637u, 6653u, 6659u, 6661u, 6673u, 6679u, 6689u,
    65521u, 65537u, 65539u, 65543u, 65551u, 65557u, 65563u, 65579u
};

// ---------------------------------------------------------------------------
// K1: one thread per (position, slot) -> hashed row index into d_ws.
// 32768 positions x 16 slots = 524288 threads. Slots 0..7 = bigram heads,
// 8..15 = trigram heads. Products < 2^47 so xor stays non-negative and
// unsigned mod == JAX floored mod.
// ---------------------------------------------------------------------------
__global__ __launch_bounds__(256)
void engram_idx_kernel(const int* __restrict__ ids,
                       const int* __restrict__ seeds,
                       int* __restrict__ idx_out)
{
    const int tid  = blockIdx.x * 256 + threadIdx.x;   // 0..524287
    const int pos  = tid >> 4;
    const int slot = tid & 15;
    const int b = pos >> 12;
    const int s = pos & 4095;

    const int* row = ids + (b << 12);
    const int id0  = row[s];
    const int idm1 = (s >= 1) ? row[s - 1] : 0;        // left zero-pad per _ngrams

    const int head = slot & 7;
    const ull sa = (ull)(unsigned)seeds[head];
    const ull sb = (ull)(unsigned)seeds[8 + head];
    ull h;
    if (slot < 8) {
        h = ((ull)(unsigned)idm1 * sa) ^ ((ull)(unsigned)id0 * sb);
    } else {
        const int idm2 = (s >= 2) ? row[s - 2] : 0;
        const ull sc = (ull)(unsigned)seeds[16 + head];
        h = ((ull)(unsigned)idm2 * sa) ^ ((ull)(unsigned)idm1 * sb)
            ^ ((ull)(unsigned)id0 * sc);
    }
    idx_out[tid] = (int)(h % (ull)kSizes[slot]);
}

// ---------------------------------------------------------------------------
// K2: one thread per output float4. Grid = 32768 positions, block = 320
// threads (5 waves): thread tx handles float4 #tx of its position's 1280-float
// output row. slot = tx/20, off = tx%20 (small-constant div -> mul magic).
// Pure load->gather->store, no hash/shfl on this path; nontemporal store keeps
// the 168 MB output stream out of L2/L3 so table rows stay cached.
// ---------------------------------------------------------------------------
__global__ __launch_bounds__(320)
void engram_gather_kernel(const int* __restrict__ idx_in,
                          const float* __restrict__ t0,  const float* __restrict__ t1,
                          const float* __restrict__ t2,  const float* __restrict__ t3,
                          const float* __restrict__ t4,  const float* __restrict__ t5,
                          const float* __restrict__ t6,  const float* __restrict__ t7,
                          const float* __restrict__ t8,  const float* __restrict__ t9,
                          const float* __restrict__ t10, const float* __restrict__ t11,
                          const float* __restrict__ t12, const float* __restrict__ t13,
                          const float* __restrict__ t14, const float* __restrict__ t15,
                          f4* __restrict__ out)
{
    __shared__ const f4* tab[16];
    if (threadIdx.x == 0) {
        tab[0]=(const f4*)t0;   tab[1]=(const f4*)t1;   tab[2]=(const f4*)t2;   tab[3]=(const f4*)t3;
        tab[4]=(const f4*)t4;   tab[5]=(const f4*)t5;   tab[6]=(const f4*)t6;   tab[7]=(const f4*)t7;
        tab[8]=(const f4*)t8;   tab[9]=(const f4*)t9;   tab[10]=(const f4*)t10; tab[11]=(const f4*)t11;
        tab[12]=(const f4*)t12; tab[13]=(const f4*)t13; tab[14]=(const f4*)t14; tab[15]=(const f4*)t15;
    }
    __syncthreads();

    const int pos  = blockIdx.x;          // 0..32767
    const int tx   = threadIdx.x;         // 0..319
    const int slot = tx / 20;             // 0..15
    const int off  = tx - slot * 20;      // float4 offset within the 80-float row

    const int ridx = idx_in[pos * 16 + slot];
    const f4  v    = tab[slot][ridx * 20 + off];   // max index 65578*20+19 < 2^31

    __builtin_nontemporal_store(v, out + (size_t)pos * 320 + tx);
}

extern "C" void kernel_launch(void* const* d_in, const int* in_sizes, int n_in,
                              void* d_out, int out_size, void* d_ws, size_t ws_size,
                              hipStream_t stream) {
    const int* ids   = (const int*)d_in[0];
    const int* seeds = (const int*)d_in[1];
    const float* t[16];
    for (int i = 0; i < 16; ++i) t[i] = (const float*)d_in[2 + i];

    int* idx_buf = (int*)d_ws;   // 524288 ints = 2 MiB of workspace

    engram_idx_kernel<<<dim3(2048), dim3(256), 0, stream>>>(ids, seeds, idx_buf);

    engram_gather_kernel<<<dim3(32768), dim3(320), 0, stream>>>(
        idx_buf,
        t[0], t[1], t[2], t[3], t[4], t[5], t[6], t[7],
        t[8], t[9], t[10], t[11], t[12], t[13], t[14], t[15],
        (f4*)d_out);
}